// Round 1
// baseline (159.908 us; speedup 1.0000x reference)
//
#include <hip/hip_runtime.h>
#include <hip/hip_bf16.h>

#define NB 2
#define ND 1024
#define NL 4096
#define NFS 4
#define NDEPTH 11
#define LN_EPS 1e-5f

#define BM 128
#define BN 128
#define BK 32

typedef __bf16 bf16x8 __attribute__((ext_vector_type(8)));
typedef float f32x4 __attribute__((ext_vector_type(4)));

__device__ __forceinline__ unsigned short f2bf(float f) {
    __hip_bfloat16 h = __float2bfloat16(f);
    unsigned short u;
    __builtin_memcpy(&u, &h, 2);
    return u;
}

__device__ __forceinline__ unsigned int pack2bf(float lo, float hi) {
    return (unsigned int)f2bf(lo) | ((unsigned int)f2bf(hi) << 16);
}

// ---------------------------------------------------------------- K0: W -> bf16
__global__ __launch_bounds__(256) void wconv_kernel(const float* __restrict__ w,
                                                    unsigned short* __restrict__ wbf) {
    const int idx8 = (blockIdx.x * 256 + threadIdx.x) * 8;
    const float4 v0 = *reinterpret_cast<const float4*>(w + idx8);
    const float4 v1 = *reinterpret_cast<const float4*>(w + idx8 + 4);
    uint4 o;
    o.x = pack2bf(v0.x, v0.y);
    o.y = pack2bf(v0.z, v0.w);
    o.z = pack2bf(v1.x, v1.y);
    o.w = pack2bf(v1.z, v1.w);
    *reinterpret_cast<uint4*>(wbf + idx8) = o;
}

// ------------------------------------------------- K1: dilated conv cascade + gating
// one block per (b*ND + d) row; row lives in LDS; thread t owns positions i*256+t
__global__ __launch_bounds__(256) void conv_cascade_kernel(const float* __restrict__ x,
                                                           const float* __restrict__ h0,
                                                           const float* __restrict__ h1,
                                                           unsigned short* __restrict__ ybf) {
    __shared__ float a_sh[NL];  // 16 KiB
    const int row = blockIdx.x;          // b*ND + d
    const int d = row & (ND - 1);
    const int t = threadIdx.x;
    const float* xrow = x + (size_t)row * NL;

    float h0c[NFS], h1c[NFS];
#pragma unroll
    for (int k = 0; k < NFS; ++k) {
        h0c[k] = h0[d * NFS + k];
        h1c[k] = h1[d * NFS + k];
    }

    float cur[16], yacc[16], bprev[16];
#pragma unroll
    for (int i = 0; i < 16; ++i) {
        cur[i] = xrow[i * 256 + t];
        a_sh[i * 256 + t] = cur[i];
        yacc[i] = 0.f;
        bprev[i] = 0.f;
    }
    __syncthreads();

    int dil = 1;
    for (int lev = 0; lev < NDEPTH; ++lev) {
        float anew[16], bnew[16];
#pragma unroll
        for (int i = 0; i < 16; ++i) {
            const int l = i * 256 + t;
            const float a0 = cur[i];  // own value, no LDS read
            const float a1 = (l >= dil)     ? a_sh[l - dil]     : 0.f;
            const float a2 = (l >= 2 * dil) ? a_sh[l - 2 * dil] : 0.f;
            const float a3 = (l >= 3 * dil) ? a_sh[l - 3 * dil] : 0.f;
            // out[l] = sum_k h[k] * a[l-(3-k)*dil]
            anew[i] = h0c[3] * a0 + h0c[2] * a1 + h0c[1] * a2 + h0c[0] * a3;
            bnew[i] = h1c[3] * a0 + h1c[2] * a1 + h1c[1] * a2 + h1c[0] * a3;
        }
        __syncthreads();  // all reads of a_sh done
#pragma unroll
        for (int i = 0; i < 16; ++i) a_sh[i * 256 + t] = anew[i];
        __syncthreads();  // writes visible for next level

        if (lev >= 1) {
            // y += sigmoid(a^{(lev+1)}) * b_{lev-1}; the lev==1 pair is counted twice
            const float sc = (lev == 1) ? 2.f : 1.f;
#pragma unroll
            for (int i = 0; i < 16; ++i) {
                const float sg = 1.f / (1.f + __expf(-anew[i]));
                yacc[i] += sc * sg * bprev[i];
            }
        }
#pragma unroll
        for (int i = 0; i < 16; ++i) {
            cur[i] = anew[i];
            bprev[i] = bnew[i];
        }
        dil <<= 1;
    }
#pragma unroll
    for (int i = 0; i < 16; ++i)
        ybf[(size_t)row * NL + i * 256 + t] = f2bf(yacc[i]);
}

// ------------------------------------------- K2: y [b][c][l] bf16 -> yT [b][l][c] bf16
__global__ __launch_bounds__(256) void transpose_kernel(const unsigned short* __restrict__ ybf,
                                                        unsigned short* __restrict__ yT) {
    __shared__ unsigned short tile[64][66];  // +2 pad breaks bank aliasing on read
    const int l0 = blockIdx.x * 64;
    const int c0 = blockIdx.y * 64;
    const int b = blockIdx.z;
    const int t = threadIdx.x;
    const int li = t & 63, cg = t >> 6;  // cg 0..3
#pragma unroll
    for (int k = 0; k < 16; ++k) {
        const int ci = cg * 16 + k;
        tile[ci][li] = ybf[(size_t)(b * ND + c0 + ci) * NL + l0 + li];
    }
    __syncthreads();
    const int ci2 = t & 63, lg = t >> 6;
#pragma unroll
    for (int k = 0; k < 16; ++k) {
        const int li2 = lg * 16 + k;
        yT[((size_t)b * NL + l0 + li2) * ND + c0 + ci2] = tile[ci2][li2];
    }
}

// --------------------------- K3: z[b][o][l] = (W @ y)[o][l] + b_mix[o] + x[b][o][l]
// bf16 MFMA 16x16x32; A = W [o][c] row-major, B = yT [l][c] (k-contiguous both sides)
__global__ __launch_bounds__(256) void gemm_kernel(const unsigned short* __restrict__ wbf,
                                                   const unsigned short* __restrict__ yT,
                                                   const float* __restrict__ x,
                                                   const float* __restrict__ bmix,
                                                   float* __restrict__ z) {
    __shared__ unsigned short As[BM][BK];  // 8 KiB
    __shared__ unsigned short Bs[BN][BK];  // 8 KiB  (stored [n][k])

    const int n0 = blockIdx.x * BN;
    const int m0 = blockIdx.y * BM;
    const int b = blockIdx.z;
    const int t = threadIdx.x;
    const int lane = t & 63, wid = t >> 6;
    const int wr = wid >> 1, wc = wid & 1;  // 2x2 waves, each 64x64
    const int fr = lane & 15;               // fragment row/col
    const int fk = (lane >> 4) * 8;         // k offset within fragment
    const int srow = t >> 1, sh = (t & 1) * 16;  // staging map: 16 shorts/thread

    f32x4 acc[4][4];
#pragma unroll
    for (int mi = 0; mi < 4; ++mi)
#pragma unroll
        for (int ni = 0; ni < 4; ++ni)
            acc[mi][ni] = (f32x4){0.f, 0.f, 0.f, 0.f};

    const unsigned short* Ag = wbf + (size_t)(m0 + srow) * ND + sh;
    const unsigned short* Bg = yT + ((size_t)b * NL + n0 + srow) * ND + sh;

    for (int kt = 0; kt < ND; kt += BK) {
        *reinterpret_cast<uint4*>(&As[srow][sh]) = *reinterpret_cast<const uint4*>(Ag + kt);
        *reinterpret_cast<uint4*>(&As[srow][sh + 8]) = *reinterpret_cast<const uint4*>(Ag + kt + 8);
        *reinterpret_cast<uint4*>(&Bs[srow][sh]) = *reinterpret_cast<const uint4*>(Bg + kt);
        *reinterpret_cast<uint4*>(&Bs[srow][sh + 8]) = *reinterpret_cast<const uint4*>(Bg + kt + 8);
        __syncthreads();

        bf16x8 af[4], bv[4];
#pragma unroll
        for (int mi = 0; mi < 4; ++mi)
            af[mi] = *reinterpret_cast<const bf16x8*>(&As[wr * 64 + mi * 16 + fr][fk]);
#pragma unroll
        for (int ni = 0; ni < 4; ++ni)
            bv[ni] = *reinterpret_cast<const bf16x8*>(&Bs[wc * 64 + ni * 16 + fr][fk]);
#pragma unroll
        for (int mi = 0; mi < 4; ++mi)
#pragma unroll
            for (int ni = 0; ni < 4; ++ni)
                acc[mi][ni] = __builtin_amdgcn_mfma_f32_16x16x32_bf16(af[mi], bv[ni],
                                                                      acc[mi][ni], 0, 0, 0);
        __syncthreads();
    }

    // epilogue: D[row][col], col = lane&15, row = (lane>>4)*4 + r   (m89-verified layout)
    const size_t base = (size_t)b * ND * NL;
#pragma unroll
    for (int mi = 0; mi < 4; ++mi) {
#pragma unroll
        for (int r = 0; r < 4; ++r) {
            const int o = m0 + wr * 64 + mi * 16 + (lane >> 4) * 4 + r;
            const float bm = bmix[o];
            const size_t rowbase = base + (size_t)o * NL;
#pragma unroll
            for (int ni = 0; ni < 4; ++ni) {
                const int l = n0 + wc * 64 + ni * 16 + fr;
                z[rowbase + l] = acc[mi][ni][r] + bm + x[rowbase + l];
            }
        }
    }
}

// ---------------------------------------------------- K4: LayerNorm over channels
__global__ __launch_bounds__(512) void ln_kernel(const float* __restrict__ z,
                                                 const float* __restrict__ gamma,
                                                 const float* __restrict__ beta,
                                                 float* __restrict__ out) {
    const int b = blockIdx.y;
    const int l0 = blockIdx.x * 32;
    const int tl = threadIdx.x & 31, tg = threadIdx.x >> 5;  // 16 c-groups
    const float* zb = z + (size_t)b * ND * NL;
    float s = 0.f, q = 0.f;
    for (int c = tg; c < ND; c += 16) {
        const float v = zb[(size_t)c * NL + l0 + tl];
        s += v;
        q += v * v;
    }
    __shared__ float sred[16][33], qred[16][33];
    __shared__ float mu_s[32], rs_s[32];
    sred[tg][tl] = s;
    qred[tg][tl] = q;
    __syncthreads();
    if (tg == 0) {
        float S = 0.f, Q = 0.f;
#pragma unroll
        for (int g = 0; g < 16; ++g) {
            S += sred[g][tl];
            Q += qred[g][tl];
        }
        const float mu = S * (1.f / ND);
        const float var = Q * (1.f / ND) - mu * mu;
        mu_s[tl] = mu;
        rs_s[tl] = rsqrtf(var + LN_EPS);
    }
    __syncthreads();
    const float mu = mu_s[tl], rs = rs_s[tl];
    float* ob = out + (size_t)b * ND * NL;
    for (int c = tg; c < ND; c += 16) {
        const size_t idx = (size_t)c * NL + l0 + tl;
        const float v = zb[idx];
        ob[idx] = (v - mu) * rs * gamma[c] + beta[c];
    }
}

extern "C" void kernel_launch(void* const* d_in, const int* in_sizes, int n_in,
                              void* d_out, int out_size, void* d_ws, size_t ws_size,
                              hipStream_t stream) {
    (void)in_sizes; (void)n_in; (void)out_size; (void)ws_size;
    const float* x = (const float*)d_in[0];
    const float* h0 = (const float*)d_in[1];
    const float* h1 = (const float*)d_in[2];
    const float* wmix = (const float*)d_in[3];
    const float* bmix = (const float*)d_in[4];
    const float* gamma = (const float*)d_in[5];
    const float* beta = (const float*)d_in[6];
    float* out = (float*)d_out;

    char* ws = (char*)d_ws;
    unsigned short* ybf = (unsigned short*)(ws);                              // 16 MiB
    unsigned short* yT = (unsigned short*)(ws + (size_t)16 * 1024 * 1024);    // 16 MiB
    unsigned short* wbf = (unsigned short*)(ws + (size_t)32 * 1024 * 1024);   // 2 MiB
    float* z = (float*)(ws + (size_t)34 * 1024 * 1024);                       // 32 MiB

    wconv_kernel<<<dim3(ND * ND / (256 * 8)), 256, 0, stream>>>(wmix, wbf);
    conv_cascade_kernel<<<dim3(NB * ND), 256, 0, stream>>>(x, h0, h1, ybf);
    transpose_kernel<<<dim3(NL / 64, ND / 64, NB), 256, 0, stream>>>(ybf, yT);
    gemm_kernel<<<dim3(NL / BN, ND / BM, NB), 256, 0, stream>>>(wbf, yT, x, bmix, z);
    ln_kernel<<<dim3(NL / 32, NB), 512, 0, stream>>>(z, gamma, beta, out);
}